// Round 2
// baseline (86885.083 us; speedup 1.0000x reference)
//
#include <hip/hip_runtime.h>
#include <hip/hip_bf16.h>

#define T_DIM 8192
#define O_DIM 1024
#define H_DIM 2048
#define G_DIM 6144   // 3*H
#define A_DIM 512
#define CHUNK 512    // gx rows computed per GEMM launch

// ---- workspace layout (float offsets; total < 47 MB) ----
#define OFF_GXC   0ull          // CHUNK x 3H fp32           (3,145,728 f)
#define OFF_HPP   3145728ull    // 2 x H fp32 ping-pong      (4,096 f)
#define OFF_S     3149824ull    // 8192 scores fp32
#define OFF_RED   3158016ull    // max, sum (+pad)
#define OFF_CPART 3158032ull    // 64 x 2048 fp32
#define OFF_C     3289104ull    // 2048 fp32
#define OFF_HSBF  3291152ull    // T x H bf16 (as 2 ushort per float slot)

__device__ __forceinline__ float bf2f(unsigned short u) {
  union { unsigned int i; float f; } v; v.i = ((unsigned int)u) << 16; return v.f;
}

// ---------------- Phase 1: gx chunk = obs_chunk @ W_ih^T + b_ih ----------------
#define BM 64
#define BN 64
#define BK 16
__global__ __launch_bounds__(256) void gemm_gx(
    const float* __restrict__ A,   // CHUNK x O (chunk of obs)
    const float* __restrict__ B,   // 3H x O
    const float* __restrict__ bias,
    float* __restrict__ C) {       // CHUNK x 3H
  __shared__ float As[BM][BK + 1];
  __shared__ float Bs[BN][BK + 1];
  const int bm = blockIdx.x * BM;
  const int bn = blockIdx.y * BN;
  const int tid = threadIdx.x;
  const int tr = tid / 16, tc = tid % 16;
  float acc[4][4] = {};
  for (int k0 = 0; k0 < O_DIM; k0 += BK) {
    for (int i = tid; i < BM * BK; i += 256) {
      int r = i / BK, c = i % BK;
      As[r][c] = A[(size_t)(bm + r) * O_DIM + k0 + c];
    }
    for (int i = tid; i < BN * BK; i += 256) {
      int r = i / BK, c = i % BK;
      Bs[r][c] = B[(size_t)(bn + r) * O_DIM + k0 + c];
    }
    __syncthreads();
#pragma unroll
    for (int kk = 0; kk < BK; ++kk) {
      float a[4], b[4];
#pragma unroll
      for (int i = 0; i < 4; ++i) a[i] = As[tr * 4 + i][kk];
#pragma unroll
      for (int j = 0; j < 4; ++j) b[j] = Bs[tc * 4 + j][kk];
#pragma unroll
      for (int i = 0; i < 4; ++i)
#pragma unroll
        for (int j = 0; j < 4; ++j) acc[i][j] += a[i] * b[j];
    }
    __syncthreads();
  }
#pragma unroll
  for (int i = 0; i < 4; ++i)
#pragma unroll
    for (int j = 0; j < 4; ++j) {
      int r = bm + tr * 4 + i, cc = bn + tc * 4 + j;
      C[(size_t)r * G_DIM + cc] = acc[i][j] + bias[cc];
    }
}

// ---------------- h0 = 0 ----------------
__global__ void zero_h0(float* __restrict__ h) {
  int i = blockIdx.x * blockDim.x + threadIdx.x;
  if (i < H_DIM) h[i] = 0.f;
}

// ---------------- Phase 2: one GRU step (fp32 recurrence; bf16 copy for attn) --
// grid 256 x 256 thr; block b owns i in [8b,8b+8); each wave owns 2 i's.
__global__ __launch_bounds__(256) void gru_step(
    const float* __restrict__ W_hh,    // 3H x H fp32
    const float* __restrict__ b_hh,    // 3H
    const float* __restrict__ gx_t,    // 3H (chunk row)
    const float* __restrict__ h_prev,  // H fp32
    float* __restrict__ h_out,         // H fp32
    unsigned short* __restrict__ hs_row) {  // H bf16
  __shared__ float hsh[H_DIM];
  const int tid = threadIdx.x;
  {
    const float4* hp4 = (const float4*)h_prev;
    float4* hs4 = (float4*)hsh;
    for (int i = tid; i < H_DIM / 4; i += 256) hs4[i] = hp4[i];
  }
  __syncthreads();
  const int wave = tid >> 6, lane = tid & 63;
  const int i0 = blockIdx.x * 8 + wave * 2;
  const float4* hh4 = (const float4*)hsh;
#pragma unroll
  for (int ii = 0; ii < 2; ++ii) {
    const int i = i0 + ii;
    float g[3];
#pragma unroll
    for (int rr = 0; rr < 3; ++rr) {
      const int j = rr * H_DIM + i;
      const float4* w4 = (const float4*)(W_hh + (size_t)j * H_DIM);
      float sum = 0.f;
#pragma unroll
      for (int u = 0; u < 8; ++u) {
        float4 w = w4[lane + 64 * u];
        float4 h = hh4[lane + 64 * u];
        sum += w.x * h.x + w.y * h.y + w.z * h.z + w.w * h.w;
      }
#pragma unroll
      for (int d = 32; d > 0; d >>= 1) sum += __shfl_xor(sum, d, 64);
      g[rr] = sum + b_hh[j];
    }
    if (lane == 0) {
      float r = 1.f / (1.f + expf(-(gx_t[i] + g[0])));
      float z = 1.f / (1.f + expf(-(gx_t[H_DIM + i] + g[1])));
      float n = tanhf(gx_t[2 * H_DIM + i] + r * g[2]);
      float h = (1.f - z) * n + z * hsh[i];
      h_out[i] = h;
      hs_row[i] = (unsigned short)(__bfloat16_as_ushort(__float2bfloat16(h)));
    }
  }
}

// ---------------- Phase 3a: attention scores (bf16 h_mid, fp32 h_last) --------
__global__ __launch_bounds__(256) void attn_scores(
    const unsigned short* __restrict__ hs_bf,  // T x H bf16; rows 0..n-1 are mid
    const float* __restrict__ h_last,          // H fp32
    float* __restrict__ s, int n) {
  __shared__ float hl[H_DIM];
  const int tid = threadIdx.x;
  {
    const float4* hp4 = (const float4*)h_last;
    float4* hs4 = (float4*)hl;
    for (int i = tid; i < H_DIM / 4; i += 256) hs4[i] = hp4[i];
  }
  __syncthreads();
  const int wave = tid >> 6, lane = tid & 63;
  const int t = blockIdx.x * 4 + wave;
  if (t >= n) return;
  const uint4* r4 = (const uint4*)(hs_bf + (size_t)t * H_DIM);  // 8 bf16 each
  float sum = 0.f;
#pragma unroll
  for (int u = 0; u < 4; ++u) {
    const int idx = lane + 64 * u;        // uint4 index; elems [idx*8, idx*8+8)
    uint4 v = r4[idx];
    const float* l = hl + idx * 8;
    sum += bf2f((unsigned short)(v.x & 0xffff)) * l[0];
    sum += bf2f((unsigned short)(v.x >> 16))    * l[1];
    sum += bf2f((unsigned short)(v.y & 0xffff)) * l[2];
    sum += bf2f((unsigned short)(v.y >> 16))    * l[3];
    sum += bf2f((unsigned short)(v.z & 0xffff)) * l[4];
    sum += bf2f((unsigned short)(v.z >> 16))    * l[5];
    sum += bf2f((unsigned short)(v.w & 0xffff)) * l[6];
    sum += bf2f((unsigned short)(v.w >> 16))    * l[7];
  }
#pragma unroll
  for (int d = 32; d > 0; d >>= 1) sum += __shfl_xor(sum, d, 64);
  if (lane == 0) s[t] = sum;
}

// ---------------- Phase 3b: softmax stats ----------------
__global__ __launch_bounds__(1024) void softmax_stats(
    const float* __restrict__ s, int n, float* __restrict__ red) {
  __shared__ float buf[1024];
  const int tid = threadIdx.x;
  float m = -3.4e38f;
  for (int i = tid; i < n; i += 1024) m = fmaxf(m, s[i]);
  buf[tid] = m;
  __syncthreads();
  for (int d = 512; d > 0; d >>= 1) {
    if (tid < d) buf[tid] = fmaxf(buf[tid], buf[tid + d]);
    __syncthreads();
  }
  const float mm = buf[0];
  __syncthreads();
  float sum = 0.f;
  for (int i = tid; i < n; i += 1024) sum += expf(s[i] - mm);
  buf[tid] = sum;
  __syncthreads();
  for (int d = 512; d > 0; d >>= 1) {
    if (tid < d) buf[tid] += buf[tid + d];
    __syncthreads();
  }
  if (tid == 0) { red[0] = mm; red[1] = buf[0]; }
}

// ---------------- Phase 3c: weighted sum partials (bf16 h_mid) ----------------
__global__ __launch_bounds__(256) void attn_wsum(
    const unsigned short* __restrict__ hs_bf, const float* __restrict__ s,
    const float* __restrict__ red, float* __restrict__ c_part, int n) {
  const int tid = threadIdx.x;
  const float m = red[0];
  const float inv = 1.f / red[1];
  const int tchunk = (n + 63) / 64;
  const int t0 = blockIdx.x * tchunk;
  const int t1 = min(t0 + tchunk, n);
  float acc[8] = {};
  for (int t = t0; t < t1; ++t) {
    const float w = expf(s[t] - m) * inv;
    const uint4 v = ((const uint4*)(hs_bf + (size_t)t * H_DIM))[tid];
    acc[0] += w * bf2f((unsigned short)(v.x & 0xffff));
    acc[1] += w * bf2f((unsigned short)(v.x >> 16));
    acc[2] += w * bf2f((unsigned short)(v.y & 0xffff));
    acc[3] += w * bf2f((unsigned short)(v.y >> 16));
    acc[4] += w * bf2f((unsigned short)(v.z & 0xffff));
    acc[5] += w * bf2f((unsigned short)(v.z >> 16));
    acc[6] += w * bf2f((unsigned short)(v.w & 0xffff));
    acc[7] += w * bf2f((unsigned short)(v.w >> 16));
  }
  float* dst = c_part + (size_t)blockIdx.x * H_DIM + tid * 8;
#pragma unroll
  for (int k = 0; k < 8; ++k) dst[k] = acc[k];
}

// ---------------- Phase 3d: reduce partials ----------------
__global__ __launch_bounds__(256) void reduce_c(
    const float* __restrict__ c_part, float* __restrict__ c) {
  const int i = blockIdx.x * 256 + threadIdx.x;
  float sum = 0.f;
  for (int b = 0; b < 64; ++b) sum += c_part[(size_t)b * H_DIM + i];
  c[i] = sum;
}

// ---------------- Phase 3e: output heads ----------------
__global__ __launch_bounds__(64) void logits_kernel(
    const float* __restrict__ W_o, const float* __restrict__ b_o,
    const float* __restrict__ W_d, const float* __restrict__ b_d,
    const float* __restrict__ c, float* __restrict__ out) {
  const int j = blockIdx.x;
  const int lane = threadIdx.x;
  const float* W; const float* bb; int jj;
  if (j < A_DIM) { W = W_o; bb = b_o; jj = j; }
  else { W = W_d; bb = b_d; jj = j - A_DIM; }
  const float4* w4 = (const float4*)(W + (size_t)jj * H_DIM);
  const float4* c4 = (const float4*)c;
  float sum = 0.f;
#pragma unroll
  for (int u = 0; u < 8; ++u) {
    float4 a = w4[lane + 64 * u];
    float4 b = c4[lane + 64 * u];
    sum += a.x * b.x + a.y * b.y + a.z * b.z + a.w * b.w;
  }
#pragma unroll
  for (int d = 32; d > 0; d >>= 1) sum += __shfl_xor(sum, d, 64);
  if (lane == 0) out[j] = sum + bb[jj];
}

extern "C" void kernel_launch(void* const* d_in, const int* in_sizes, int n_in,
                              void* d_out, int out_size, void* d_ws, size_t ws_size,
                              hipStream_t stream) {
  const float* obs  = (const float*)d_in[0];
  const float* W_ih = (const float*)d_in[1];
  const float* W_hh = (const float*)d_in[2];
  const float* b_ih = (const float*)d_in[3];
  const float* b_hh = (const float*)d_in[4];
  const float* W_o  = (const float*)d_in[5];
  const float* b_o  = (const float*)d_in[6];
  const float* W_d  = (const float*)d_in[7];
  const float* b_d  = (const float*)d_in[8];
  float* out = (float*)d_out;
  float* ws = (float*)d_ws;

  float* gxc    = ws + OFF_GXC;    // CHUNK x 3H, reused per chunk
  float* hpp    = ws + OFF_HPP;    // 2 x H ping-pong
  float* s      = ws + OFF_S;
  float* red    = ws + OFF_RED;
  float* c_part = ws + OFF_CPART;
  float* c      = ws + OFF_C;
  unsigned short* hs_bf = (unsigned short*)(ws + OFF_HSBF);  // T x H bf16

  zero_h0<<<(H_DIM + 255) / 256, 256, 0, stream>>>(hpp);  // pp slot 0 = h0 = 0

  // Chunked: gx GEMM for CHUNK steps, then CHUNK sequential GRU steps.
  for (int c0 = 0; c0 < T_DIM; c0 += CHUNK) {
    gemm_gx<<<dim3(CHUNK / BM, G_DIM / BN), 256, 0, stream>>>(
        obs + (size_t)c0 * O_DIM, W_ih, b_ih, gxc);
    for (int tt = 0; tt < CHUNK; ++tt) {
      const int t = c0 + tt;
      float* h_prev = hpp + (size_t)(t & 1) * H_DIM;
      float* h_out  = hpp + (size_t)((t + 1) & 1) * H_DIM;
      gru_step<<<256, 256, 0, stream>>>(W_hh, b_hh,
                                        gxc + (size_t)tt * G_DIM,
                                        h_prev, h_out,
                                        hs_bf + (size_t)t * H_DIM);
    }
  }
  // final h (after step t=8191) lives in pp slot (8192 & 1) = 0
  const float* h_last = hpp;

  // Phase 3: attention over states 0..8190 (bf16), query = fp32 h_last
  const int n = T_DIM - 1;  // 8191
  attn_scores<<<(n + 3) / 4, 256, 0, stream>>>(hs_bf, h_last, s, n);
  softmax_stats<<<1, 1024, 0, stream>>>(s, n, red);
  attn_wsum<<<64, 256, 0, stream>>>(hs_bf, s, red, c_part, n);
  reduce_c<<<H_DIM / 256, 256, 0, stream>>>(c_part, c);
  logits_kernel<<<2 * A_DIM, 64, 0, stream>>>(W_o, b_o, W_d, b_d, c, out);
}